// Round 15
// baseline (1250.788 us; speedup 1.0000x reference)
//
#include <hip/hip_runtime.h>
#include <math.h>

#define BATCH 2
#define TSEQ 1024
#define DIM 1024
#define NLAYER 12
#define EDIM 4096
#define BT 2048
#define EPS_LN 1e-5f
#define NZ2 4          // GEMM2 split-K slices

typedef __attribute__((ext_vector_type(4))) float  f32x4;
typedef __attribute__((ext_vector_type(8))) __bf16 bf16x8;
typedef __attribute__((ext_vector_type(4))) __bf16 bf16x4;

__device__ __forceinline__ void gl_lds16(const void* gptr, void* lptr) {
    __builtin_amdgcn_global_load_lds(
        (const __attribute__((address_space(1))) void*)gptr,
        (__attribute__((address_space(3))) void*)lptr,
        16, 0, 0);
}

// ---- 64x64 f32->bf16 transpose tile, one 256-thread team ------------------
__device__ __forceinline__ void wtile256(float (*t)[65], const float* src,
                                         __bf16* dst, int R, int C,
                                         int rt, int ct, int tid)
{
    int lr = tid >> 2, cs = (tid & 3) << 4;
    const float* sp = src + (size_t)(rt * 64 + lr) * C + ct * 64 + cs;
#pragma unroll
    for (int s = 0; s < 4; s++) {
        f32x4 v = *(const f32x4*)(sp + s * 4);
        t[lr][cs + s * 4 + 0] = v[0];
        t[lr][cs + s * 4 + 1] = v[1];
        t[lr][cs + s * 4 + 2] = v[2];
        t[lr][cs + s * 4 + 3] = v[3];
    }
    __syncthreads();
    int oc = tid >> 2, rs = (tid & 3) << 4;
    bf16x8 o0, o1;
#pragma unroll
    for (int e = 0; e < 8; e++) o0[e] = (__bf16)t[rs + e][oc];
#pragma unroll
    for (int e = 0; e < 8; e++) o1[e] = (__bf16)t[rs + 8 + e][oc];
    __bf16* dp = dst + (size_t)(ct * 64 + oc) * R + rt * 64 + rs;
    *(bf16x8*)dp = o0;
    *(bf16x8*)(dp + 8) = o1;
}

// ----------------------------------------- standalone wtrans (layer 0) ----
__global__ __launch_bounds__(256) void wtrans_kernel(
    const float* __restrict__ W1, const float* __restrict__ W2,
    __bf16* __restrict__ W1t, __bf16* __restrict__ W2t)
{
    __shared__ float t[64][65];
    int z = blockIdx.z;
    if (z == 0) wtile256(t, W1, W1t, DIM, EDIM, blockIdx.y, blockIdx.x, threadIdx.x);
    else        wtile256(t, W2, W2t, EDIM, DIM, blockIdx.x, blockIdx.y, threadIdx.x);
}

// ---------------- fused: attn (blocks 0..2047) + wtrans (2048..4095) -------
__global__ __launch_bounds__(256)
void attn_wt_kernel(const float* __restrict__ x,
                    const __bf16* __restrict__ baseprev,
                    __bf16* __restrict__ histbf,
                    const __bf16* __restrict__ part,
                    const float* __restrict__ q,
                    const float* __restrict__ kng,
                    const float* __restrict__ knb,
                    const float* __restrict__ lng,
                    const float* __restrict__ lnb,
                    const float* __restrict__ b2,
                    __bf16* __restrict__ hnext,
                    __bf16* __restrict__ u,
                    int nl,
                    const float* __restrict__ W1n,
                    const float* __restrict__ W2n,
                    __bf16* __restrict__ W1tn,
                    __bf16* __restrict__ W2tn,
                    int dowt)
{
    __shared__ char smem[49408];

    if (blockIdx.x >= BT) {
        if (!dowt) return;
        float (*t)[65] = (float(*)[65])smem;
        int tile = blockIdx.x - BT;
        if (tile < 1024) wtile256(t, W1n, W1tn, DIM, EDIM, tile >> 6, tile & 63, threadIdx.x);
        else { int t3 = tile - 1024; wtile256(t, W2n, W2tn, EDIM, DIM, t3 & 63, t3 >> 6, threadIdx.x); }
        return;
    }

    float (*V)[DIM] = (float(*)[DIM])smem;                    // [12][1024]
    float* sS  = (float*)(smem + 49152);
    float* sMu = sS + NLAYER;
    float* sRs = sMu + NLAYER;

    const int bt = blockIdx.x;
    const int tid = threadIdx.x, lane = tid & 63, w = tid >> 6;

    f32x4 gqv[4];
    float sg = 0.f, sb = 0.f;
#pragma unroll
    for (int i = 0; i < 4; i++) {
        int d = i * 256 + lane * 4;
        f32x4 g4 = *(const f32x4*)(kng + d);
        f32x4 q4 = *(const f32x4*)(q + d);
        f32x4 b4 = *(const f32x4*)(knb + d);
#pragma unroll
        for (int c = 0; c < 4; c++) {
            float gq = g4[c] * q4[c];
            gqv[i][c] = gq;
            sg += gq;
            sb += b4[c] * q4[c];
        }
    }
#pragma unroll
    for (int off = 32; off; off >>= 1) {
        sg += __shfl_xor(sg, off);
        sb += __shfl_xor(sb, off);
    }

    for (int lp = w; lp < nl; lp += 4) {
        f32x4 vv[4];
        if (lp == nl - 1) {
            if (nl == 1) {
                const float* vp = x + (size_t)bt * DIM;
#pragma unroll
                for (int i = 0; i < 4; i++) vv[i] = *(const f32x4*)(vp + i * 256 + lane * 4);
            } else {
                const __bf16* vp = baseprev + (size_t)bt * DIM;
#pragma unroll
                for (int i = 0; i < 4; i++) {
                    bf16x4 b4 = *(const bf16x4*)(vp + i * 256 + lane * 4);
#pragma unroll
                    for (int c = 0; c < 4; c++) vv[i][c] = (float)b4[c];
                }
            }
            if (part) {
#pragma unroll
                for (int z = 0; z < NZ2; z++) {
                    const __bf16* pp = part + ((size_t)z * BT + bt) * DIM;
#pragma unroll
                    for (int i = 0; i < 4; i++) {
                        bf16x4 p4 = *(const bf16x4*)(pp + i * 256 + lane * 4);
#pragma unroll
                        for (int c = 0; c < 4; c++) vv[i][c] += (float)p4[c];
                    }
                }
            }
            if (nl < NLAYER) {
                __bf16* mp = histbf + ((size_t)lp * BT + bt) * DIM;
#pragma unroll
                for (int i = 0; i < 4; i++) {
                    bf16x4 m4;
#pragma unroll
                    for (int c = 0; c < 4; c++) m4[c] = (__bf16)vv[i][c];
                    *(bf16x4*)(mp + i * 256 + lane * 4) = m4;
                }
            }
        } else {
            const __bf16* mp = histbf + ((size_t)lp * BT + bt) * DIM;
#pragma unroll
            for (int i = 0; i < 4; i++) {
                bf16x4 m4 = *(const bf16x4*)(mp + i * 256 + lane * 4);
#pragma unroll
                for (int c = 0; c < 4; c++) vv[i][c] = (float)m4[c];
            }
        }

        float s1 = 0.f, s2 = 0.f, sq = 0.f;
#pragma unroll
        for (int i = 0; i < 4; i++) {
            *(f32x4*)(&V[lp][i * 256 + lane * 4]) = vv[i];
#pragma unroll
            for (int c = 0; c < 4; c++) {
                float xv = vv[i][c];
                s1 += xv; s2 += xv * xv; sq += xv * gqv[i][c];
            }
        }
#pragma unroll
        for (int off = 32; off; off >>= 1) {
            s1 += __shfl_xor(s1, off);
            s2 += __shfl_xor(s2, off);
            sq += __shfl_xor(sq, off);
        }
        if (lane == 0) {
            float mu = s1 * (1.0f / DIM);
            float var = s2 * (1.0f / DIM) - mu * mu;
            float rs = rsqrtf(var + EPS_LN);
            sMu[lp] = mu; sRs[lp] = rs;
            sS[lp] = (rs * (sq - mu * sg) + sb) * (1.0f / 32.0f);
        }
    }
    __syncthreads();

    float mx = -1e30f;
#pragma unroll
    for (int i = 0; i < NLAYER; i++) if (i < nl) mx = fmaxf(mx, sS[i]);
    float al[NLAYER];
    float ssum = 0.f;
#pragma unroll
    for (int i = 0; i < NLAYER; i++) {
        al[i] = (i < nl) ? __expf(sS[i] - mx) : 0.f;
        ssum += al[i];
    }
    float inv = 1.0f / ssum;

    const int d = tid * 4;
    f32x4 r; r[0] = 0.f; r[1] = 0.f; r[2] = 0.f; r[3] = 0.f;
#pragma unroll
    for (int i = 0; i < NLAYER; i++) {
        if (i < nl) {
            f32x4 v4 = *(const f32x4*)(&V[i][d]);
            float a = al[i] * inv;
            r[0] += a * v4[0]; r[1] += a * v4[1]; r[2] += a * v4[2]; r[3] += a * v4[3];
        }
    }
    f32x4 h4 = *(const f32x4*)(&V[nl - 1][d]);
    f32x4 b24 = *(const f32x4*)(b2 + d);
    bf16x4 ho;
#pragma unroll
    for (int c = 0; c < 4; c++) ho[c] = (__bf16)(r[c] + b24[c]);
    *(bf16x4*)(hnext + (size_t)bt * DIM + d) = ho;

    float mu = sMu[nl - 1], rs = sRs[nl - 1];
    f32x4 g4 = *(const f32x4*)(lng + d);
    f32x4 b4 = *(const f32x4*)(lnb + d);
    bf16x4 uo;
#pragma unroll
    for (int c = 0; c < 4; c++) uo[c] = (__bf16)((h4[c] - mu) * rs * g4[c] + b4[c]);
    *(bf16x4*)(u + (size_t)bt * DIM + d) = uo;
}

// ------------------------------------------------------------------ GEMM ---
// C = A(bf16 MxK) * Bt(bf16 NxK)^T.  256x256 tile, 8 waves (128x64 each),
// BK=32 units, 4-slot cyclic LDS (128 KB), prefetch depth 3, counted
// vmcnt(8) (outstanding never < 8 wave-loads => HBM pipe stays saturated
// even at 128 blocks), one barrier per unit, setprio around MFMA.
// Unit u's slot = u&3; stage(u+3) targets slot (u-1)&3 whose readers all
// passed this iteration's barrier => race-free. Staging keeps gemm8-style
// coalescing (4 lanes cover 64 contiguous bytes per row) with XOR source
// pre-swizzle so frag ds_read_b128 is <=4-way (HBM-bound; irrelevant).
// Halves staged bytes vs 128x256: GEMM1 192->96 MB, GEMM2 192->128 MB.
// EPI==0: bf16 gelu(acc+bias) -> hmid. EPI==2: bf16 split-K partial slice.
#define NU 32          // K=1024 per block / 32

template <int EPI>
__global__ __launch_bounds__(512, 1)
void gemm256k32(const __bf16* __restrict__ A, const __bf16* __restrict__ Bt,
                const float* __restrict__ bias, void* __restrict__ outp,
                int N, int As, int Bs)
{
    __shared__ char lds[131072];           // 4 slots x (A 16KB + B 16KB)
    const int tid = threadIdx.x, lane = tid & 63, w = tid >> 6;
    const int wm = w >> 2, wn = w & 3;     // 2M x 4N wave grid
    const int lr = lane & 15;
    const int hib = (lane >> 4) << 4;      // k-octet byte

    const int fid = blockIdx.x;
    int m0, n0, kbase, zsl;
    if (EPI == 0) {                        // 8m x 16n tiles = 128 blocks
        m0 = (fid >> 4) * 256; n0 = (fid & 15) * 256; kbase = 0; zsl = 0;
    } else {                               // 8m x 4n x 4z = 128 blocks
        zsl = fid & 3;
        m0 = ((fid >> 2) & 7) * 256; n0 = (fid >> 5) * 256; kbase = zsl * 1024;
    }

    f32x4 acc[8][4];
#pragma unroll
    for (int i = 0; i < 8; i++)
#pragma unroll
        for (int j = 0; j < 4; j++) { acc[i][j][0]=0.f; acc[i][j][1]=0.f; acc[i][j][2]=0.f; acc[i][j][3]=0.f; }

    // staging: per operand 2 loads/thread/unit: idx = l*512+tid in [0,1024);
    // row = idx>>2 (0..255), q = idx&3; source k-byte = (q*16)^((row&3)<<4)
    // so LDS (linear dest) holds octet o at row*64 + (o^(row&3))*16.
    const char* Ac = (const char*)A;
    const char* Bc = (const char*)Bt;
    size_t ag[2], bg[2];
    int ldso[2];
#pragma unroll
    for (int l = 0; l < 2; l++) {
        int idx = l * 512 + tid;
        int row = idx >> 2, qq = idx & 3;
        int ksw = (qq * 16) ^ ((row & 3) << 4);
        ag[l] = ((size_t)(m0 + row) * As + kbase) * 2 + ksw;
        bg[l] = ((size_t)(n0 + row) * Bs + kbase) * 2 + ksw;
        ldso[l] = l * 8192 + w * 1024;     // wave-uniform dest base offset
    }

    auto STAGE = [&](int uu, int slot) {
        size_t kb = (size_t)uu * 64;       // 32 elems * 2B along K
        char* sa = lds + slot * 32768;
        char* sbp = sa + 16384;
#pragma unroll
        for (int l = 0; l < 2; l++) gl_lds16(Ac + ag[l] + kb, sa + ldso[l]);
#pragma unroll
        for (int l = 0; l < 2; l++) gl_lds16(Bc + bg[l] + kb, sbp + ldso[l]);
    };

    STAGE(0, 0);
    STAGE(1, 1);
    STAGE(2, 2);

#pragma unroll 1
    for (int u = 0; u < NU; ++u) {
        if (u < NU - 2)       asm volatile("s_waitcnt vmcnt(8)" ::: "memory");
        else if (u == NU - 2) asm volatile("s_waitcnt vmcnt(4)" ::: "memory");
        else                  asm volatile("s_waitcnt vmcnt(0)" ::: "memory");
        __builtin_amdgcn_s_barrier();
        __builtin_amdgcn_sched_barrier(0);

        if (u + 3 < NU) STAGE(u + 3, (u + 3) & 3);

        const char* sa = lds + (u & 3) * 32768;
        const char* sbp = sa + 16384;
        bf16x8 bfr[4], afr[8];
#pragma unroll
        for (int j = 0; j < 4; j++) {
            int row = wn * 64 + j * 16 + lr;
            bfr[j] = *(const bf16x8*)(sbp + row * 64 + (hib ^ ((row & 3) << 4)));
        }
#pragma unroll
        for (int i = 0; i < 8; i++) {
            int row = wm * 128 + i * 16 + lr;
            afr[i] = *(const bf16x8*)(sa + row * 64 + (hib ^ ((row & 3) << 4)));
        }
        __builtin_amdgcn_s_setprio(1);
#pragma unroll
        for (int i = 0; i < 8; i++)
#pragma unroll
            for (int j = 0; j < 4; j++)
                acc[i][j] = __builtin_amdgcn_mfma_f32_16x16x32_bf16(afr[i], bfr[j], acc[i][j], 0, 0, 0);
        __builtin_amdgcn_s_setprio(0);
    }

    const int lrow = (lane >> 4) << 2;
    if (EPI == 0) {
        __bf16* out = (__bf16*)outp;
#pragma unroll
        for (int i = 0; i < 8; i++) {
#pragma unroll
            for (int j = 0; j < 4; j++) {
                int colg = n0 + wn * 64 + j * 16 + lr;
                float bc = bias[colg];
#pragma unroll
                for (int r = 0; r < 4; r++) {
                    int rowg = m0 + wm * 128 + i * 16 + lrow + r;
                    float v = acc[i][j][r] + bc;
                    float tt2 = 0.7978845608f * (v + 0.044715f * v * v * v);
                    float e = __expf(2.0f * tt2);
                    float th = 1.0f - 2.0f / (e + 1.0f);
                    out[(size_t)rowg * N + colg] = (__bf16)(0.5f * v * (1.0f + th));
                }
            }
        }
    } else {
        __bf16* out = (__bf16*)outp + (size_t)zsl * BT * N;
#pragma unroll
        for (int i = 0; i < 8; i++) {
#pragma unroll
            for (int j = 0; j < 4; j++) {
                int colg = n0 + wn * 64 + j * 16 + lr;
#pragma unroll
                for (int r = 0; r < 4; r++) {
                    int rowg = m0 + wm * 128 + i * 16 + lrow + r;
                    out[(size_t)rowg * N + colg] = (__bf16)acc[i][j][r];
                }
            }
        }
    }
}

// ------------------------------------- final assembly (layer 12) -> d_out --
__global__ void final_reduce(const __bf16* __restrict__ base,
                             const __bf16* __restrict__ part,
                             float* __restrict__ out)
{
    size_t i = ((size_t)blockIdx.x * 256 + threadIdx.x) * 4;
    bf16x4 b4 = *(const bf16x4*)(base + i);
    f32x4 r;
#pragma unroll
    for (int c = 0; c < 4; c++) r[c] = (float)b4[c];
#pragma unroll
    for (int z = 0; z < NZ2; z++) {
        bf16x4 p = *(const bf16x4*)(part + (size_t)z * BT * DIM + i);
#pragma unroll
        for (int c = 0; c < 4; c++) r[c] += (float)p[c];
    }
    *(f32x4*)(out + i) = r;
}

// ---------------------------------------------------------------- launch ---
extern "C" void kernel_launch(void* const* d_in, const int* in_sizes, int n_in,
                              void* d_out, int out_size, void* d_ws, size_t ws_size,
                              hipStream_t stream)
{
    const float* x   = (const float*)d_in[0];
    const float* q   = (const float*)d_in[1];
    const float* kng = (const float*)d_in[2];
    const float* knb = (const float*)d_in[3];
    const float* lng = (const float*)d_in[4];
    const float* lnb = (const float*)d_in[5];
    const float* W1  = (const float*)d_in[6];
    const float* b1  = (const float*)d_in[7];
    const float* W2  = (const float*)d_in[8];
    const float* b2  = (const float*)d_in[9];

    char* ws = (char*)d_ws;
    const size_t MB = 1048576;
    __bf16* base2[2] = { (__bf16*)(ws), (__bf16*)(ws + 4 * MB) };  // bf16 ping-pong
    __bf16* histbf = (__bf16*)(ws + 8 * MB);         // 12 bf16 slots: 48 MB
    __bf16* ubuf   = (__bf16*)(ws + 56 * MB);        // 4 MB
    __bf16* hmid   = (__bf16*)(ws + 60 * MB);        // 16 MB
    __bf16* W1tb[2] = { (__bf16*)(ws + 76 * MB), (__bf16*)(ws + 84 * MB) };
    __bf16* W2tb[2] = { (__bf16*)(ws + 92 * MB), (__bf16*)(ws + 100 * MB) };
    __bf16* part   = (__bf16*)(ws + 108 * MB);       // NZ2 x 4 MB (end 124 MB)

    wtrans_kernel<<<dim3(64, 16, 2), 256, 0, stream>>>(W1, W2, W1tb[0], W2tb[0]);

    for (int l = 0; l < NLAYER; l++) {
        int nl = l + 1;
        int ln = (l + 1 < NLAYER) ? l + 1 : l;
        __bf16* hnext = base2[l & 1];
        const __bf16* bprev = base2[(l + 1) & 1];
        attn_wt_kernel<<<dim3(2 * BT), 256, 0, stream>>>(
            x, bprev, histbf, (l >= 1) ? part : (const __bf16*)nullptr,
            q + (size_t)l * DIM,
            kng + (size_t)l * DIM, knb + (size_t)l * DIM,
            lng + (size_t)l * DIM, lnb + (size_t)l * DIM,
            b2 + (size_t)l * DIM, hnext, ubuf, nl,
            W1 + (size_t)ln * DIM * EDIM, W2 + (size_t)ln * EDIM * DIM,
            W1tb[(l + 1) & 1], W2tb[(l + 1) & 1], (l + 1 < NLAYER) ? 1 : 0);
        gemm256k32<0><<<dim3(128), 512, 0, stream>>>(
            ubuf, W1tb[l & 1], b1 + (size_t)l * EDIM, (void*)hmid, EDIM, DIM, DIM);
        gemm256k32<2><<<dim3(128), 512, 0, stream>>>(
            hmid, W2tb[l & 1], nullptr, (void*)part, DIM, EDIM, EDIM);
    }

    final_reduce<<<dim3(BT * DIM / 1024), 256, 0, stream>>>(
        base2[1], part, (float*)d_out);
}

// Round 16
// 865.675 us; speedup vs baseline: 1.4449x; 1.4449x over previous
//
#include <hip/hip_runtime.h>
#include <math.h>

#define BATCH 2
#define TSEQ 1024
#define DIM 1024
#define NLAYER 12
#define EDIM 4096
#define BT 2048
#define EPS_LN 1e-5f
#define NZ2 4          // GEMM2 split-K slices

typedef __attribute__((ext_vector_type(4))) float  f32x4;
typedef __attribute__((ext_vector_type(8))) __bf16 bf16x8;
typedef __attribute__((ext_vector_type(4))) __bf16 bf16x4;

__device__ __forceinline__ void gl_lds16(const void* gptr, void* lptr) {
    __builtin_amdgcn_global_load_lds(
        (const __attribute__((address_space(1))) void*)gptr,
        (__attribute__((address_space(3))) void*)lptr,
        16, 0, 0);
}

// ---- 64x64 f32->bf16 transpose tile, one 256-thread team ------------------
__device__ __forceinline__ void wtile256(float (*t)[65], const float* src,
                                         __bf16* dst, int R, int C,
                                         int rt, int ct, int tid)
{
    int lr = tid >> 2, cs = (tid & 3) << 4;
    const float* sp = src + (size_t)(rt * 64 + lr) * C + ct * 64 + cs;
#pragma unroll
    for (int s = 0; s < 4; s++) {
        f32x4 v = *(const f32x4*)(sp + s * 4);
        t[lr][cs + s * 4 + 0] = v[0];
        t[lr][cs + s * 4 + 1] = v[1];
        t[lr][cs + s * 4 + 2] = v[2];
        t[lr][cs + s * 4 + 3] = v[3];
    }
    __syncthreads();
    int oc = tid >> 2, rs = (tid & 3) << 4;
    bf16x8 o0, o1;
#pragma unroll
    for (int e = 0; e < 8; e++) o0[e] = (__bf16)t[rs + e][oc];
#pragma unroll
    for (int e = 0; e < 8; e++) o1[e] = (__bf16)t[rs + 8 + e][oc];
    __bf16* dp = dst + (size_t)(ct * 64 + oc) * R + rt * 64 + rs;
    *(bf16x8*)dp = o0;
    *(bf16x8*)(dp + 8) = o1;
}

// ----------------------------------------- standalone wtrans (layer 0) ----
__global__ __launch_bounds__(256) void wtrans_kernel(
    const float* __restrict__ W1, const float* __restrict__ W2,
    __bf16* __restrict__ W1t, __bf16* __restrict__ W2t)
{
    __shared__ float t[64][65];
    int z = blockIdx.z;
    if (z == 0) wtile256(t, W1, W1t, DIM, EDIM, blockIdx.y, blockIdx.x, threadIdx.x);
    else        wtile256(t, W2, W2t, EDIM, DIM, blockIdx.x, blockIdx.y, threadIdx.x);
}

// ---------------- fused: attn (blocks 0..2047) + wtrans (2048..4095) -------
__global__ __launch_bounds__(256)
void attn_wt_kernel(const float* __restrict__ x,
                    const __bf16* __restrict__ baseprev,
                    __bf16* __restrict__ histbf,
                    const __bf16* __restrict__ part,
                    const float* __restrict__ q,
                    const float* __restrict__ kng,
                    const float* __restrict__ knb,
                    const float* __restrict__ lng,
                    const float* __restrict__ lnb,
                    const float* __restrict__ b2,
                    __bf16* __restrict__ hnext,
                    __bf16* __restrict__ u,
                    int nl,
                    const float* __restrict__ W1n,
                    const float* __restrict__ W2n,
                    __bf16* __restrict__ W1tn,
                    __bf16* __restrict__ W2tn,
                    int dowt)
{
    __shared__ char smem[49408];

    if (blockIdx.x >= BT) {
        if (!dowt) return;
        float (*t)[65] = (float(*)[65])smem;
        int tile = blockIdx.x - BT;
        if (tile < 1024) wtile256(t, W1n, W1tn, DIM, EDIM, tile >> 6, tile & 63, threadIdx.x);
        else { int t3 = tile - 1024; wtile256(t, W2n, W2tn, EDIM, DIM, t3 & 63, t3 >> 6, threadIdx.x); }
        return;
    }

    float (*V)[DIM] = (float(*)[DIM])smem;                    // [12][1024]
    float* sS  = (float*)(smem + 49152);
    float* sMu = sS + NLAYER;
    float* sRs = sMu + NLAYER;

    const int bt = blockIdx.x;
    const int tid = threadIdx.x, lane = tid & 63, w = tid >> 6;

    f32x4 gqv[4];
    float sg = 0.f, sb = 0.f;
#pragma unroll
    for (int i = 0; i < 4; i++) {
        int d = i * 256 + lane * 4;
        f32x4 g4 = *(const f32x4*)(kng + d);
        f32x4 q4 = *(const f32x4*)(q + d);
        f32x4 b4 = *(const f32x4*)(knb + d);
#pragma unroll
        for (int c = 0; c < 4; c++) {
            float gq = g4[c] * q4[c];
            gqv[i][c] = gq;
            sg += gq;
            sb += b4[c] * q4[c];
        }
    }
#pragma unroll
    for (int off = 32; off; off >>= 1) {
        sg += __shfl_xor(sg, off);
        sb += __shfl_xor(sb, off);
    }

    for (int lp = w; lp < nl; lp += 4) {
        f32x4 vv[4];
        if (lp == nl - 1) {
            if (nl == 1) {
                const float* vp = x + (size_t)bt * DIM;
#pragma unroll
                for (int i = 0; i < 4; i++) vv[i] = *(const f32x4*)(vp + i * 256 + lane * 4);
            } else {
                const __bf16* vp = baseprev + (size_t)bt * DIM;
#pragma unroll
                for (int i = 0; i < 4; i++) {
                    bf16x4 b4 = *(const bf16x4*)(vp + i * 256 + lane * 4);
#pragma unroll
                    for (int c = 0; c < 4; c++) vv[i][c] = (float)b4[c];
                }
            }
            if (part) {
#pragma unroll
                for (int z = 0; z < NZ2; z++) {
                    const __bf16* pp = part + ((size_t)z * BT + bt) * DIM;
#pragma unroll
                    for (int i = 0; i < 4; i++) {
                        bf16x4 p4 = *(const bf16x4*)(pp + i * 256 + lane * 4);
#pragma unroll
                        for (int c = 0; c < 4; c++) vv[i][c] += (float)p4[c];
                    }
                }
            }
            if (nl < NLAYER) {
                __bf16* mp = histbf + ((size_t)lp * BT + bt) * DIM;
#pragma unroll
                for (int i = 0; i < 4; i++) {
                    bf16x4 m4;
#pragma unroll
                    for (int c = 0; c < 4; c++) m4[c] = (__bf16)vv[i][c];
                    *(bf16x4*)(mp + i * 256 + lane * 4) = m4;
                }
            }
        } else {
            const __bf16* mp = histbf + ((size_t)lp * BT + bt) * DIM;
#pragma unroll
            for (int i = 0; i < 4; i++) {
                bf16x4 m4 = *(const bf16x4*)(mp + i * 256 + lane * 4);
#pragma unroll
                for (int c = 0; c < 4; c++) vv[i][c] = (float)m4[c];
            }
        }

        float s1 = 0.f, s2 = 0.f, sq = 0.f;
#pragma unroll
        for (int i = 0; i < 4; i++) {
            *(f32x4*)(&V[lp][i * 256 + lane * 4]) = vv[i];
#pragma unroll
            for (int c = 0; c < 4; c++) {
                float xv = vv[i][c];
                s1 += xv; s2 += xv * xv; sq += xv * gqv[i][c];
            }
        }
#pragma unroll
        for (int off = 32; off; off >>= 1) {
            s1 += __shfl_xor(s1, off);
            s2 += __shfl_xor(s2, off);
            sq += __shfl_xor(sq, off);
        }
        if (lane == 0) {
            float mu = s1 * (1.0f / DIM);
            float var = s2 * (1.0f / DIM) - mu * mu;
            float rs = rsqrtf(var + EPS_LN);
            sMu[lp] = mu; sRs[lp] = rs;
            sS[lp] = (rs * (sq - mu * sg) + sb) * (1.0f / 32.0f);
        }
    }
    __syncthreads();

    float mx = -1e30f;
#pragma unroll
    for (int i = 0; i < NLAYER; i++) if (i < nl) mx = fmaxf(mx, sS[i]);
    float al[NLAYER];
    float ssum = 0.f;
#pragma unroll
    for (int i = 0; i < NLAYER; i++) {
        al[i] = (i < nl) ? __expf(sS[i] - mx) : 0.f;
        ssum += al[i];
    }
    float inv = 1.0f / ssum;

    const int d = tid * 4;
    f32x4 r; r[0] = 0.f; r[1] = 0.f; r[2] = 0.f; r[3] = 0.f;
#pragma unroll
    for (int i = 0; i < NLAYER; i++) {
        if (i < nl) {
            f32x4 v4 = *(const f32x4*)(&V[i][d]);
            float a = al[i] * inv;
            r[0] += a * v4[0]; r[1] += a * v4[1]; r[2] += a * v4[2]; r[3] += a * v4[3];
        }
    }
    f32x4 h4 = *(const f32x4*)(&V[nl - 1][d]);
    f32x4 b24 = *(const f32x4*)(b2 + d);
    bf16x4 ho;
#pragma unroll
    for (int c = 0; c < 4; c++) ho[c] = (__bf16)(r[c] + b24[c]);
    *(bf16x4*)(hnext + (size_t)bt * DIM + d) = ho;

    float mu = sMu[nl - 1], rs = sRs[nl - 1];
    f32x4 g4 = *(const f32x4*)(lng + d);
    f32x4 b4 = *(const f32x4*)(lnb + d);
    bf16x4 uo;
#pragma unroll
    for (int c = 0; c < 4; c++) uo[c] = (__bf16)((h4[c] - mu) * rs * g4[c] + b4[c]);
    *(bf16x4*)(u + (size_t)bt * DIM + d) = uo;
}

// ------------------------------------------------------------------ GEMM ---
// C = A(bf16 MxK) * Bt(bf16 NxK)^T.  128x256 tile, 8 waves (64x64 each),
// BK=64, triple-buffered LDS, prefetch depth 2, counted vmcnt(6), setprio.
// ROUND-ROBIN-aware L2 rectangles: HW assigns XCD = blockIdx % 8; blocks
// with the same residue form an 8m x 4n rectangle (GEMM1: 4 MB = L2/XCD)
// or a 4m x 2n rectangle per split-K slice (GEMM2: 2 MB per (xcd,z)).
// EPI==0: bf16 gelu(acc+bias) -> hmid. EPI==2: bf16 split-K partial slice,
// 1D grid with z decoded from block id.
#define STG 49152   // A 16KB + B 32KB per stage

template <int EPI>
__global__ __launch_bounds__(512, 1)
void gemm8(const __bf16* __restrict__ A, const __bf16* __restrict__ Bt,
           const float* __restrict__ bias, void* __restrict__ outp,
           int N, int As, int Bs)
{
    __shared__ char lds[3 * STG];          // 144 KB
    const int tid = threadIdx.x, lane = tid & 63, w = tid >> 6;
    const int wm = w >> 2, wn = w & 3;
    const int lr = lane & 15;
    const int hib = (lane >> 4) << 4;
    const int NT = 16;

    const int fid = blockIdx.x;
    const int xcd = fid & 7;
    const int c = fid >> 3;                // 0..31
    int m0, n0, kbase, zsl;
    if (EPI == 0) {
        // 16m x 16n tiles; rect(xcd) = 8m x 4n
        int mi = ((xcd & 1) << 3) + (c & 7);
        int ni = ((xcd >> 1) << 2) + (c >> 3);
        m0 = mi * 128; n0 = ni * 256; kbase = 0; zsl = 0;
    } else {
        // 16m x 4n tiles x 4 z; rect(xcd,z) = 4m x 2n
        zsl = c & 3;
        int local = c >> 2;                // 0..7
        int mi = ((xcd & 3) << 2) + (local & 3);
        int ni = ((xcd >> 2) << 1) + (local >> 2);
        m0 = mi * 128; n0 = ni * 256; kbase = zsl * 1024;
    }

    f32x4 acc[4][4];
#pragma unroll
    for (int i = 0; i < 4; i++)
#pragma unroll
        for (int j2 = 0; j2 < 4; j2++) { acc[i][j2][0]=0.f; acc[i][j2][1]=0.f; acc[i][j2][2]=0.f; acc[i][j2][3]=0.f; }

    const int srow = tid >> 3;
    const int ksrc = ((tid & 7) << 4) ^ ((srow & 7) << 4);
    const char* Ac = (const char*)A;
    const char* Bc = (const char*)Bt;
    size_t aoff[2], boff[4];
#pragma unroll
    for (int cc = 0; cc < 2; cc++)
        aoff[cc] = ((size_t)(m0 + cc * 64 + srow) * As + kbase) * 2 + ksrc;
#pragma unroll
    for (int cc = 0; cc < 4; cc++)
        boff[cc] = ((size_t)(n0 + cc * 64 + srow) * Bs + kbase) * 2 + ksrc;

    char* abw = lds + w * 1024;
    char* bbw = lds + 16384 + w * 1024;

    auto STAGE = [&](int tt, int bi) {
        size_t kb = (size_t)tt * 128;
        char* ab = abw + bi * STG;
        char* bb = bbw + bi * STG;
#pragma unroll
        for (int cc = 0; cc < 2; cc++) gl_lds16(Ac + aoff[cc] + kb, ab + cc * 8192);
#pragma unroll
        for (int cc = 0; cc < 4; cc++) gl_lds16(Bc + boff[cc] + kb, bb + cc * 8192);
    };

    STAGE(0, 0);
    STAGE(1, 1);

    int sb = 0, st = 2;
#pragma unroll 1
    for (int t = 0; t < NT; ++t) {
        if (t < NT - 1) asm volatile("s_waitcnt vmcnt(6)" ::: "memory");
        else            asm volatile("s_waitcnt vmcnt(0)" ::: "memory");
        __builtin_amdgcn_s_barrier();
        __builtin_amdgcn_sched_barrier(0);

        if (t + 2 < NT) STAGE(t + 2, st);

        const char* base = lds + sb * STG;
        bf16x8 af[2][4], bfr[2][4];
#pragma unroll
        for (int kk = 0; kk < 2; kk++) {
#pragma unroll
            for (int i = 0; i < 4; i++) {
                int ra = wm * 64 + i * 16 + lr;
                af[kk][i] = *(const bf16x8*)(base + ra * 128 + ((kk * 64 + hib) ^ ((ra & 7) << 4)));
            }
#pragma unroll
            for (int j2 = 0; j2 < 4; j2++) {
                int rb = wn * 64 + j2 * 16 + lr;
                bfr[kk][j2] = *(const bf16x8*)(base + 16384 + rb * 128 + ((kk * 64 + hib) ^ ((rb & 7) << 4)));
            }
        }
        __builtin_amdgcn_s_setprio(1);
#pragma unroll
        for (int kk = 0; kk < 2; kk++)
#pragma unroll
            for (int i = 0; i < 4; i++)
#pragma unroll
                for (int j2 = 0; j2 < 4; j2++)
                    acc[i][j2] = __builtin_amdgcn_mfma_f32_16x16x32_bf16(af[kk][i], bfr[kk][j2], acc[i][j2], 0, 0, 0);
        __builtin_amdgcn_s_setprio(0);

        sb = (sb == 2) ? 0 : sb + 1;
        st = (st == 2) ? 0 : st + 1;
    }

    const int lrow = (lane >> 4) << 2;
    if (EPI == 0) {
        __bf16* out = (__bf16*)outp;
#pragma unroll
        for (int i = 0; i < 4; i++) {
#pragma unroll
            for (int j2 = 0; j2 < 4; j2++) {
                int colg = n0 + wn * 64 + j2 * 16 + lr;
                float bc = bias[colg];
#pragma unroll
                for (int r = 0; r < 4; r++) {
                    int rowg = m0 + wm * 64 + i * 16 + lrow + r;
                    float v = acc[i][j2][r] + bc;
                    float tt2 = 0.7978845608f * (v + 0.044715f * v * v * v);
                    float e = __expf(2.0f * tt2);
                    float th = 1.0f - 2.0f / (e + 1.0f);
                    out[(size_t)rowg * N + colg] = (__bf16)(0.5f * v * (1.0f + th));
                }
            }
        }
    } else {
        __bf16* out = (__bf16*)outp + (size_t)zsl * BT * N;
#pragma unroll
        for (int i = 0; i < 4; i++) {
#pragma unroll
            for (int j2 = 0; j2 < 4; j2++) {
                int colg = n0 + wn * 64 + j2 * 16 + lr;
#pragma unroll
                for (int r = 0; r < 4; r++) {
                    int rowg = m0 + wm * 64 + i * 16 + lrow + r;
                    out[(size_t)rowg * N + colg] = (__bf16)acc[i][j2][r];
                }
            }
        }
    }
}

// ------------------------------------- final assembly (layer 12) -> d_out --
__global__ void final_reduce(const __bf16* __restrict__ base,
                             const __bf16* __restrict__ part,
                             float* __restrict__ out)
{
    size_t i = ((size_t)blockIdx.x * 256 + threadIdx.x) * 4;
    bf16x4 b4 = *(const bf16x4*)(base + i);
    f32x4 r;
#pragma unroll
    for (int c = 0; c < 4; c++) r[c] = (float)b4[c];
#pragma unroll
    for (int z = 0; z < NZ2; z++) {
        bf16x4 p = *(const bf16x4*)(part + (size_t)z * BT * DIM + i);
#pragma unroll
        for (int c = 0; c < 4; c++) r[c] += (float)p[c];
    }
    *(f32x4*)(out + i) = r;
}

// ---------------------------------------------------------------- launch ---
extern "C" void kernel_launch(void* const* d_in, const int* in_sizes, int n_in,
                              void* d_out, int out_size, void* d_ws, size_t ws_size,
                              hipStream_t stream)
{
    const float* x   = (const float*)d_in[0];
    const float* q   = (const float*)d_in[1];
    const float* kng = (const float*)d_in[2];
    const float* knb = (const float*)d_in[3];
    const float* lng = (const float*)d_in[4];
    const float* lnb = (const float*)d_in[5];
    const float* W1  = (const float*)d_in[6];
    const float* b1  = (const float*)d_in[7];
    const float* W2  = (const float*)d_in[8];
    const float* b2  = (const float*)d_in[9];

    char* ws = (char*)d_ws;
    const size_t MB = 1048576;
    __bf16* base2[2] = { (__bf16*)(ws), (__bf16*)(ws + 4 * MB) };  // bf16 ping-pong
    __bf16* histbf = (__bf16*)(ws + 8 * MB);         // 12 bf16 slots: 48 MB
    __bf16* ubuf   = (__bf16*)(ws + 56 * MB);        // 4 MB
    __bf16* hmid   = (__bf16*)(ws + 60 * MB);        // 16 MB
    __bf16* W1tb[2] = { (__bf16*)(ws + 76 * MB), (__bf16*)(ws + 84 * MB) };
    __bf16* W2tb[2] = { (__bf16*)(ws + 92 * MB), (__bf16*)(ws + 100 * MB) };
    __bf16* part   = (__bf16*)(ws + 108 * MB);       // NZ2 x 4 MB (end 124 MB)

    wtrans_kernel<<<dim3(64, 16, 2), 256, 0, stream>>>(W1, W2, W1tb[0], W2tb[0]);

    for (int l = 0; l < NLAYER; l++) {
        int nl = l + 1;
        int ln = (l + 1 < NLAYER) ? l + 1 : l;
        __bf16* hnext = base2[l & 1];
        const __bf16* bprev = base2[(l + 1) & 1];
        attn_wt_kernel<<<dim3(2 * BT), 256, 0, stream>>>(
            x, bprev, histbf, (l >= 1) ? part : (const __bf16*)nullptr,
            q + (size_t)l * DIM,
            kng + (size_t)l * DIM, knb + (size_t)l * DIM,
            lng + (size_t)l * DIM, lnb + (size_t)l * DIM,
            b2 + (size_t)l * DIM, hnext, ubuf, nl,
            W1 + (size_t)ln * DIM * EDIM, W2 + (size_t)ln * EDIM * DIM,
            W1tb[(l + 1) & 1], W2tb[(l + 1) & 1], (l + 1 < NLAYER) ? 1 : 0);
        gemm8<0><<<dim3(256), 512, 0, stream>>>(
            ubuf, W1tb[l & 1], b1 + (size_t)l * EDIM, (void*)hmid, EDIM, DIM, DIM);
        gemm8<2><<<dim3(256), 512, 0, stream>>>(
            hmid, W2tb[l & 1], nullptr, (void*)part, DIM, EDIM, EDIM);
    }

    final_reduce<<<dim3(BT * DIM / 1024), 256, 0, stream>>>(
        base2[1], part, (float*)d_out);
}